// Round 8
// baseline (88.147 us; speedup 1.0000x reference)
//
#include <hip/hip_runtime.h>
#include <float.h>
#include <math.h>

#pragma clang fp contract(off)

#define R 8192
#define NCLS 80
#define SC 81          // scores row width (K+1)
#define TOPK_N 100
#define SCORE_THRESH 0.05f
#define NMS_THRESH 0.5f

// workspace layout (bytes)
#define BOXC_OFF   0            // float4[R]                 131072
#define ENT_OFF    131072       // u64 entries[8000]         64000  -> 195072
#define CCNT_OFF   195072       // int ccnt[80]              320    -> 195392
#define COUNTS_OFF 195584       // u32 counts[80][256]       81920  -> 277504
#define CKEYS_OFF  277760       // u64 ckeys[80][8192]       5242880
#define NENT       (NCLS * TOPK_N)   // 8000

__device__ __forceinline__ bool finitef(float x) {
    return fabsf(x) <= FLT_MAX;   // false for NaN and +-inf
}

__device__ __forceinline__ float iou_f(float4 a, float aa, float4 b, float ab) {
    float ltx = fmaxf(a.x, b.x), lty = fmaxf(a.y, b.y);
    float rbx = fminf(a.z, b.z), rby = fminf(a.w, b.w);
    float iw = fmaxf(rbx - ltx, 0.f), ih = fmaxf(rby - lty, 0.f);
    float inter = iw * ih;
    float uni = aa + ab - inter + 1e-9f;
    return inter / uni;
}

__device__ __forceinline__ float area_of(float4 b) {
    return fmaxf(b.z - b.x, 0.f) * fmaxf(b.w - b.y, 0.f);
}

// key packing: (score_bits << 13) | (8191 - r)  -> u64 desc == (score desc, r asc)
__device__ __forceinline__ unsigned long long pack_key(float sc, int r) {
    return ((unsigned long long)__float_as_uint(sc) << 13) |
           (unsigned long long)(8191 - r);
}

// ------------- kernel A: prep (clip, validity) + fused per-class compaction -------
#define PREP_ROWS 32
#define PREP_THREADS 256

__global__ __launch_bounds__(PREP_THREADS) void prep_kernel(
    const float* __restrict__ boxes,
    const float* __restrict__ scores,
    const int* __restrict__ imh,
    const int* __restrict__ imw,
    float4* __restrict__ boxes_c,
    unsigned long long* __restrict__ entries,
    unsigned long long* __restrict__ ckeys,
    unsigned int* __restrict__ counts) {
    __shared__ float4 s_sc4[PREP_ROWS * SC / 4];            // 648 float4 = 10368 B
    __shared__ int s_vld[PREP_ROWS];
    __shared__ int s_ccnt[NCLS];
    __shared__ unsigned long long s_ckey[NCLS][PREP_ROWS];  // 20 KB

    const int tid = threadIdx.x;
    const int blk = blockIdx.x;
    const int r0 = blk * PREP_ROWS;
    float* s_sc = (float*)s_sc4;

    {   // zero the 8000 entry slots across the first 32 blocks
        int i = blk * PREP_THREADS + tid;
        if (i < NENT) entries[i] = 0ull;
    }
    if (tid < PREP_ROWS) s_vld[tid] = 1;
    if (tid < NCLS) s_ccnt[tid] = 0;
    __syncthreads();

    // coalesced float4 load of 32 rows x 81 scores (2592 floats = 648 float4)
    const float4* src4 = (const float4*)(scores + (size_t)r0 * SC);
    for (int idx = tid; idx < PREP_ROWS * SC / 4; idx += PREP_THREADS) {
        float4 v = src4[idx];
        s_sc4[idx] = v;
        int e = idx * 4;
        if (!finitef(v.x)) atomicAnd(&s_vld[(e + 0) / SC], 0);
        if (!finitef(v.y)) atomicAnd(&s_vld[(e + 1) / SC], 0);
        if (!finitef(v.z)) atomicAnd(&s_vld[(e + 2) / SC], 0);
        if (!finitef(v.w)) atomicAnd(&s_vld[(e + 3) / SC], 0);
    }

    // boxes: 32 coalesced float4 loads, clip, store
    if (tid < PREP_ROWS) {
        float4 b = ((const float4*)boxes)[r0 + tid];
        bool bok = finitef(b.x) && finitef(b.y) && finitef(b.z) && finitef(b.w);
        float w = (float)(*imw), h = (float)(*imh);
        float4 bc;
        bc.x = fminf(fmaxf(b.x, 0.f), w);
        bc.y = fminf(fmaxf(b.y, 0.f), h);
        bc.z = fminf(fmaxf(b.z, 0.f), w);
        bc.w = fminf(fmaxf(b.w, 0.f), h);
        boxes_c[r0 + tid] = bc;
        if (!bok) atomicAnd(&s_vld[tid], 0);
    }
    __syncthreads();

    // per-class compaction within this block's 32 rows (block-owned segments)
    for (int idx = tid; idx < NCLS * PREP_ROWS; idx += PREP_THREADS) {
        int k = idx >> 5, rr = idx & 31;
        float sc = s_sc[rr * SC + k];
        if (sc > SCORE_THRESH && s_vld[rr]) {
            int p = atomicAdd(&s_ccnt[k], 1);
            s_ckey[k][p] = pack_key(sc, r0 + rr);
        }
    }
    __syncthreads();

    if (tid < NCLS) counts[(size_t)tid * 256 + blk] = (unsigned int)s_ccnt[tid];
    for (int idx = tid; idx < NCLS * PREP_ROWS; idx += PREP_THREADS) {
        int k = idx >> 5, m = idx & 31;
        if (m < s_ccnt[k])
            ckeys[((size_t)k << 13) + (blk << 5) + m] = s_ckey[k][m];
    }
}

// ------------- kernel B: per-class gather + sort + mask-matrix greedy NMS ---------
#define NMS_THREADS 256
#define KMAX 192

template <int U>
__device__ __forceinline__ void rank_sort_inplace(unsigned long long* s_key,
                                                  int cnt, int tid) {
    unsigned long long kv[U];
    int rk[U];
#pragma unroll
    for (int m = 0; m < U; ++m) {
        int i = tid + (m << 8);
        kv[m] = (i < cnt) ? s_key[i] : 0ull;
        rk[m] = 0;
    }
    if (tid < cnt) {
        int j = 0;
        for (; j + 2 <= cnt; j += 2) {
            unsigned long long a = s_key[j], b = s_key[j + 1];
#pragma unroll
            for (int m = 0; m < U; ++m)
                rk[m] += (int)(a > kv[m]) + (int)(b > kv[m]);
        }
        if (j < cnt) {
            unsigned long long a = s_key[j];
#pragma unroll
            for (int m = 0; m < U; ++m) rk[m] += (int)(a > kv[m]);
        }
    }
    __syncthreads();
#pragma unroll
    for (int m = 0; m < U; ++m) {
        int i = tid + (m << 8);
        if (i < cnt) s_key[rk[m]] = kv[m];   // ranks are a permutation (unique keys)
    }
}

__global__ __launch_bounds__(NMS_THREADS) void nms_kernel(
    const unsigned long long* __restrict__ ckeys,
    const unsigned int* __restrict__ counts,
    const float4* __restrict__ boxes_c,
    unsigned long long* __restrict__ entries,
    int* __restrict__ ccnt) {
    __shared__ unsigned long long s_key[R];        // 64 KB (sorted candidate keys)
    __shared__ float4 s_cb[256];                   // 4 KB  top-256 candidate boxes
    __shared__ float  s_ca[256];                   // 1 KB
    __shared__ unsigned long long s_masks[256][4]; // 8 KB  upper-tri IoU bitmask
    __shared__ float4 kb[KMAX];                    // kept boxes (for fallback)
    __shared__ float  ka[KMAX];
    __shared__ float4 s_stg[64];                   // fallback chunk staging
    __shared__ float  s_sca[64];
    __shared__ unsigned int s_part[4][64];
    __shared__ unsigned int s_sup1[4][64];
    __shared__ unsigned int s_cntb[256];
    __shared__ unsigned int s_pref[256];
    __shared__ unsigned int s_wsum[4];
    __shared__ int s_flag;
    __shared__ int s_kept;

    const int tid = threadIdx.x;
    const int k = blockIdx.x;
    const int lane = tid & 63;
    const int wv = tid >> 6;

    if (tid == 0) { s_flag = 0; s_kept = 0; }
    __syncthreads();

    // ---- counts row + block-wide exclusive prefix (wave shfl scan) ----
    unsigned int cb_ = counts[((size_t)k << 8) + tid];
    s_cntb[tid] = cb_;
    unsigned int v = cb_;
#pragma unroll
    for (int d = 1; d < 64; d <<= 1) {
        unsigned int o = __shfl_up(v, d);
        if (lane >= d) v += o;
    }
    if (lane == 63) s_wsum[wv] = v;
    if (cb_ > 8) s_flag = 1;        // benign race, any writer sets 1
    __syncthreads();
    unsigned int offs = 0;
    for (int w2 = 0; w2 < wv; ++w2) offs += s_wsum[w2];
    s_pref[tid] = offs + v - cb_;
    const int cnt = (int)(s_wsum[0] + s_wsum[1] + s_wsum[2] + s_wsum[3]);
    __syncthreads();

    if (cnt == 0) {
        if (tid == 0) ccnt[k] = 0;
        return;
    }

    // ---- gather keys from 256 block-segments into LDS (one-shot, predicated) ----
    const unsigned long long* ck = ckeys + ((size_t)k << 13);
    for (int idx = tid; idx < 2048; idx += NMS_THREADS) {
        int b = idx >> 3, m = idx & 7;
        if ((unsigned)m < s_cntb[b]) s_key[s_pref[b] + m] = ck[(b << 5) + m];
    }
    if (s_flag) {   // rare: some block contributed >8 candidates for this class
        for (int b = 0; b < 256; ++b) {
            int c2 = (int)s_cntb[b];
            for (int m = 8 + tid; m < c2; m += NMS_THREADS)
                s_key[s_pref[b] + m] = ck[(b << 5) + m];
        }
    }
    __syncthreads();

    // ---- sort (rank-sort tiers; bitonic fallback for cnt > 2048) ----
    if (cnt <= 256) {
        rank_sort_inplace<1>(s_key, cnt, tid);
    } else if (cnt <= 512) {
        rank_sort_inplace<2>(s_key, cnt, tid);
    } else if (cnt <= 1024) {
        rank_sort_inplace<4>(s_key, cnt, tid);
    } else if (cnt <= 2048) {
        rank_sort_inplace<8>(s_key, cnt, tid);
    } else {
        int npad = 4096;
        while (npad < cnt) npad <<= 1;
        for (int i = cnt + tid; i < npad; i += NMS_THREADS) s_key[i] = 0ull;
        __syncthreads();
        for (int kk = 2; kk <= npad; kk <<= 1) {
            for (int j = kk >> 1; j > 0; j >>= 1) {
                for (int i = tid; i < npad; i += NMS_THREADS) {
                    int ixj = i ^ j;
                    if (ixj > i) {
                        unsigned long long a = s_key[i], b = s_key[ixj];
                        bool ascending = ((i & kk) == 0);
                        if ((b > a) == ascending) { s_key[i] = b; s_key[ixj] = a; }
                    }
                }
                __syncthreads();
            }
        }
    }
    __syncthreads();

    // ---- one-shot gather of top-W boxes; areas recomputed in-register ----
    const int Wc = cnt < 256 ? cnt : 256;
    if (tid < Wc) {
        int b = 8191 - (int)(s_key[tid] & 8191ull);
        float4 cb = boxes_c[b];
        s_cb[tid] = cb;
        s_ca[tid] = area_of(cb);
    }
    __syncthreads();

    // ---- upper-triangle 256x256 IoU bitmask matrix (no barriers inside) ----
    {
        float4 bi = s_cb[tid];
        float ai = s_ca[tid];
#pragma unroll
        for (int w2 = 0; w2 < 4; ++w2) {
            unsigned long long mw = 0ull;
            int j0 = tid + 1 > (w2 << 6) ? tid + 1 : (w2 << 6);
            int j1 = Wc < ((w2 + 1) << 6) ? Wc : ((w2 + 1) << 6);
            for (int j = j0; j < j1; ++j)
                if (iou_f(bi, ai, s_cb[j], s_ca[j]) > NMS_THRESH)
                    mw |= 1ull << (j & 63);
            s_masks[tid][w2] = mw;
        }
    }
    __syncthreads();

    // ---- wave0: barrier-free greedy resolve over up to 4 chunks ----
    if (tid < 64) {
        const int l = lane;
        const unsigned long long lbit = 1ull << l;
        unsigned long long dead1 = 0, dead2 = 0, dead3 = 0;
        int keptTot = 0;
        bool done = false;
        const int nW = (Wc + 63) >> 6;
#pragma unroll
        for (int c = 0; c < 4; ++c) {
            if (c < nW && !done) {
                const int j = (c << 6) + l;
                unsigned long long dc = (c == 0) ? 0ull
                                       : (c == 1) ? dead1
                                       : (c == 2) ? dead2 : dead3;
                bool alive0 = (j < cnt) && !((dc >> l) & 1ull);
                unsigned long long mw0 = s_masks[j][0];
                unsigned long long mw1 = s_masks[j][1];
                unsigned long long mw2 = s_masks[j][2];
                unsigned long long mw3 = s_masks[j][3];
                unsigned long long mc = (c == 0) ? mw0
                                       : (c == 1) ? mw1
                                       : (c == 2) ? mw2 : mw3;
                unsigned long long av = __ballot(alive0);
                unsigned long long kept = 0ull, deadIn = 0ull;
                for (int lp = 0; lp < 64; ++lp) {
                    unsigned long long m = __shfl(mc, lp);   // indep of carried state
                    unsigned long long bit = 1ull << lp;
                    if ((av & bit) && !(deadIn & bit)) { kept |= bit; deadIn |= m; }
                }
                int kc2 = __popcll(kept);
                int excess = keptTot + kc2 - TOPK_N;
                while (excess > 0) {   // trim latest keeps past the 100th (uniform)
                    kept &= ~(1ull << (63 - __clzll(kept)));
                    --excess;
                }
                kc2 = __popcll(kept);
                if (kept & lbit) {
                    int pos = keptTot + (int)__popcll(kept & (lbit - 1ull));
                    unsigned long long kv = s_key[j];
                    int bidx = 8191 - (int)(kv & 8191ull);
                    entries[k * TOPK_N + pos] =
                        ((unsigned long long)(unsigned int)(k * R + bidx) << 32) |
                        (kv >> 13);
                    kb[pos] = s_cb[j];
                    ka[pos] = s_ca[j];
                }
                keptTot += kc2;
                if (keptTot >= TOPK_N) {
                    done = true;
                } else {
                    unsigned long long c1 = (kept & lbit) ? mw1 : 0ull;
                    unsigned long long c2 = (kept & lbit) ? mw2 : 0ull;
                    unsigned long long c3 = (kept & lbit) ? mw3 : 0ull;
#pragma unroll
                    for (int off = 32; off > 0; off >>= 1) {
                        c1 |= __shfl_xor(c1, off);
                        c2 |= __shfl_xor(c2, off);
                        c3 |= __shfl_xor(c3, off);
                    }
                    dead1 |= c1; dead2 |= c2; dead3 |= c3;
                }
            }
        }
        if (l == 0) s_kept = keptTot;
    }
    __syncthreads();

    // ---- rare fallback: >256 candidates consumed before 100 keeps ----
    const int nchunks = (cnt + 63) >> 6;
    for (int c = 4; c < nchunks; ++c) {
        const int kept0 = s_kept;
        if (kept0 >= TOPK_N) break;    // uniform
        const int j = (c << 6) + lane;
        const bool incand = (j < cnt);

        if (tid < 64) {
            float4 cb = make_float4(0.f, 0.f, 0.f, 0.f);
            if (incand) {
                int b = 8191 - (int)(s_key[j] & 8191ull);
                cb = boxes_c[b];
            }
            s_stg[lane] = cb;
            s_sca[lane] = area_of(cb);
        }
        __syncthreads();

        {
            float4 cb = s_stg[lane];
            float car = s_sca[lane];
            unsigned int sup = 0u;
            for (int t = wv; t < kept0; t += 4)
                if (iou_f(cb, car, kb[t], ka[t]) > NMS_THRESH) sup = 1u;
            s_sup1[wv][lane] = sup;
            unsigned int pm = 0u;
            const int i0 = wv << 4;
#pragma unroll
            for (int ii = 0; ii < 16; ++ii) {
                int i = i0 + ii;
                if (i != lane && iou_f(cb, car, s_stg[i], s_sca[i]) > NMS_THRESH)
                    pm |= 1u << ii;
            }
            s_part[wv][lane] = pm;
        }
        __syncthreads();

        if (tid < 64) {
            bool sup1 = (s_sup1[0][lane] | s_sup1[1][lane] |
                         s_sup1[2][lane] | s_sup1[3][lane]) != 0u;
            unsigned long long supmask =
                 (unsigned long long)s_part[0][lane]
               | ((unsigned long long)s_part[1][lane] << 16)
               | ((unsigned long long)s_part[2][lane] << 32)
               | ((unsigned long long)s_part[3][lane] << 48);
            bool alive0 = incand && !sup1;
            unsigned long long av = __ballot(alive0);
            unsigned long long kept = 0ull;
#pragma unroll
            for (int l = 0; l < 64; ++l) {
                unsigned long long m = __shfl(supmask, l);
                if (((av >> l) & 1ull) && !(m & kept)) kept |= 1ull << l;
            }
            if ((kept >> lane) & 1ull) {
                int pos = kept0 + (int)__popcll(kept & ((1ull << lane) - 1ull));
                if (pos < KMAX) {
                    kb[pos] = s_stg[lane];
                    ka[pos] = s_sca[lane];
                }
                if (pos < TOPK_N) {
                    unsigned long long kv = s_key[j];
                    int bidx = 8191 - (int)(kv & 8191ull);
                    entries[k * TOPK_N + pos] =
                        ((unsigned long long)(unsigned int)(k * R + bidx) << 32) |
                        (kv >> 13);
                }
            }
            if (lane == 0) s_kept = kept0 + (int)__popcll(kept);
        }
        __syncthreads();
    }

    if (tid == 0) {
        int kf = s_kept;
        ccnt[k] = kf < TOPK_N ? kf : TOPK_N;
    }
}

// ---------------- kernel C: radix-select top-100 of 8000 + output ----------------
#define TK_THREADS 256
#define TIECAP 512

__global__ __launch_bounds__(TK_THREADS) void topk_kernel(
    const unsigned long long* __restrict__ entries,
    const int* __restrict__ ccnt,
    const float4* __restrict__ boxes_c,
    float* __restrict__ out) {
    __shared__ unsigned int hist[4 * 1024];   // wave-private, 16 KB
    __shared__ unsigned int wt[4];
    __shared__ unsigned int s_binr[2];        // {bin, remaining rank}
    __shared__ unsigned int selk[TOPK_N];
    __shared__ int          selp[TOPK_N];
    __shared__ unsigned int fkey[TOPK_N];
    __shared__ int          fpos[TOPK_N];
    __shared__ int          tiepos[TIECAP];
    __shared__ unsigned int a_gt, a_tie;
    __shared__ int s_M;

    const int tid = threadIdx.x;
    const int wave = tid >> 6, lane = tid & 63;
    const unsigned int* e32 = (const unsigned int*)entries;

    unsigned int key[32];
#pragma unroll
    for (int i = 0; i < 32; ++i) {
        int idx = i * TK_THREADS + tid;
        key[i] = (idx < NENT) ? e32[2 * idx] : 0u;
    }
    if (tid == 0) { a_gt = 0u; a_tie = 0u; s_M = 0; }
    if (tid < TOPK_N) { fkey[tid] = 0u; fpos[tid] = 0; }
    __syncthreads();
    if (tid < NCLS) atomicAdd(&s_M, ccnt[tid]);   // ccnt already capped at 100
    __syncthreads();
    const int M = s_M;

    unsigned int T = 0u;
    unsigned int needed_ties = 0u;
    if (M >= TOPK_N) {
        unsigned int r = TOPK_N;
        unsigned int P = 0x0Fu;       // keys are floats in (0.05,1]: bits 31..26
        int hi = 26;
        const int nbits_arr[3] = {8, 8, 10};
        for (int lvl = 0; lvl < 3; ++lvl) {
            const int nbits = nbits_arr[lvl];
            const int nb = 1 << nbits;
            const int sh = hi - nbits;
            for (int j = tid; j < 4 * 1024; j += TK_THREADS) hist[j] = 0u;
            __syncthreads();
            unsigned int* hw = &hist[wave * 1024];
#pragma unroll
            for (int i = 0; i < 32; ++i) {
                unsigned int kv = key[i];
                if ((kv >> hi) == P) atomicAdd(&hw[(kv >> sh) & (nb - 1)], 1u);
            }
            __syncthreads();
            const int G = nb >> 8;
            unsigned int g = 0u;
            for (int b = 0; b < G; ++b) {
                int bin = tid * G + b;
                g += hist[bin] + hist[1024 + bin] + hist[2048 + bin] + hist[3072 + bin];
            }
            unsigned int S = g;
            for (int off = 1; off < 64; off <<= 1) {
                unsigned int v = __shfl_down(S, off);
                if (lane + off < 64) S += v;
            }
            if (lane == 0) wt[wave] = S;
            __syncthreads();
            unsigned int above_w = 0u;
            for (int w2 = wave + 1; w2 < 4; ++w2) above_w += wt[w2];
            unsigned int Sown = S + above_w;
            unsigned int above = Sown - g;
            if (above < r && r <= Sown) {
                unsigned int cum = above;
                for (int b = G - 1; b >= 0; --b) {
                    int bin = tid * G + b;
                    unsigned int tb = hist[bin] + hist[1024 + bin] +
                                      hist[2048 + bin] + hist[3072 + bin];
                    cum += tb;
                    if (cum >= r) {
                        s_binr[0] = (unsigned int)bin;
                        s_binr[1] = r - (cum - tb);
                        break;
                    }
                }
            }
            __syncthreads();
            P = (P << nbits) | s_binr[0];
            r = s_binr[1];
            hi = sh;
            __syncthreads();
        }
        T = P;
        needed_ties = r;
    }
    __syncthreads();

    const unsigned int Teff = (M >= TOPK_N) ? T : 0u;
    if (M > 0) {
#pragma unroll
        for (int i = 0; i < 32; ++i) {
            unsigned int kv = key[i];
            int pos = i * TK_THREADS + tid;
            if (kv > Teff) {
                unsigned int p = atomicAdd(&a_gt, 1u);
                selk[p] = kv; selp[p] = pos;
            } else if (M >= TOPK_N && kv == Teff) {
                unsigned int q = atomicAdd(&a_tie, 1u);
                if (q < TIECAP) tiepos[q] = pos;
            }
        }
    }
    __syncthreads();
    const unsigned int ngt = a_gt;
    if (M >= TOPK_N && needed_ties > 0u) {
        unsigned int ntie = a_tie < TIECAP ? a_tie : TIECAP;
        for (unsigned int j = tid; j < ntie; j += TK_THREADS) {
            int pj = tiepos[j];
            unsigned int rnk = 0u;
            for (unsigned int j2 = 0; j2 < ntie; ++j2) rnk += (tiepos[j2] < pj);
            if (rnk < needed_ties) { selk[ngt + rnk] = T; selp[ngt + rnk] = pj; }
        }
    }
    __syncthreads();

    const int SELN = (M >= TOPK_N) ? TOPK_N : M;
    if (tid < SELN) {
        unsigned int kk = selk[tid];
        int pp = selp[tid];
        unsigned int rnk = 0u;
        for (int j = 0; j < SELN; ++j) {
            unsigned int kj = selk[j];
            int pj = selp[j];
            rnk += (kj > kk) || (kj == kk && pj < pp);
        }
        fkey[rnk] = kk;
        fpos[rnk] = pp;
    }
    __syncthreads();

    if (tid < TOPK_N) {
        bool dv = (tid < SELN);
        int pos = fpos[tid];
        float s = __uint_as_float(fkey[tid]);
        int flat = dv ? (int)e32[2 * pos + 1] : 0;
        int r = flat & (R - 1);
        int kc = flat >> 13;
        float4 bb = dv ? boxes_c[r] : make_float4(0.f, 0.f, 0.f, 0.f);
        out[tid * 4 + 0] = bb.x;
        out[tid * 4 + 1] = bb.y;
        out[tid * 4 + 2] = bb.z;
        out[tid * 4 + 3] = bb.w;
        out[400 + tid] = dv ? s : 0.f;
        out[500 + tid] = dv ? (float)kc : -1.f;
        out[600 + tid] = dv ? (float)r : -1.f;
    }
}

extern "C" void kernel_launch(void* const* d_in, const int* in_sizes, int n_in,
                              void* d_out, int out_size, void* d_ws, size_t ws_size,
                              hipStream_t stream) {
    const float* boxes  = (const float*)d_in[0];
    const float* scores = (const float*)d_in[1];
    const int*   imh    = (const int*)d_in[2];
    const int*   imw    = (const int*)d_in[3];

    char* ws = (char*)d_ws;
    float4*             boxes_c = (float4*)(ws + BOXC_OFF);
    unsigned long long* entries = (unsigned long long*)(ws + ENT_OFF);
    int*                ccnt    = (int*)(ws + CCNT_OFF);
    unsigned int*       counts  = (unsigned int*)(ws + COUNTS_OFF);
    unsigned long long* ckeys   = (unsigned long long*)(ws + CKEYS_OFF);

    prep_kernel<<<R / PREP_ROWS, PREP_THREADS, 0, stream>>>(
        boxes, scores, imh, imw, boxes_c, entries, ckeys, counts);
    nms_kernel<<<NCLS, NMS_THREADS, 0, stream>>>(
        ckeys, counts, boxes_c, entries, ccnt);
    topk_kernel<<<1, TK_THREADS, 0, stream>>>(entries, ccnt, boxes_c,
                                              (float*)d_out);
}